// Round 11
// baseline (238.490 us; speedup 1.0000x reference)
//
#include <hip/hip_runtime.h>
#include <math.h>

#define N_NODES 50000
#define N_HEDGE 5000
#define N_EDGES 400000
#define NB 2
#define NC 64
#define NEG 0.2f
#define NROWS (N_NODES * NB)   // 100000

// ws note: harness poison-fill shows ws_size >= 256MB; round-6 broker failures were
// infra, not overflow. Current layout ~26.4MB.

__device__ __forceinline__ unsigned short f2bf(float f) {
    unsigned int u = __float_as_uint(f);
    unsigned int r = (u + 0x7FFFu + ((u >> 16) & 1u)) >> 16;   // RNE
    return (unsigned short)r;
}

// ---------------- GEMM: xw[row][c] bf16, row = n*2+b; epilogue p1/p2
__global__ __launch_bounds__(256, 4) void gemm_kernel(const float* __restrict__ x,
                                                      const float* __restrict__ W,
                                                      const float* __restrict__ att,
                                                      unsigned short* __restrict__ xwb,
                                                      float* __restrict__ p1,
                                                      float* __restrict__ p2)
{
    __shared__ float xs[64 * 68];
    __shared__ float Ws[64 * 68];
    int t = threadIdx.x;
    int R = blockIdx.x * 64;

#pragma unroll
    for (int i = 0; i < 4; i++) {
        int lin = t + 256 * i;
        int r = lin >> 4, c4 = lin & 15;
        float4 wv = ((const float4*)W)[lin];
        *(float4*)&Ws[r * 68 + c4 * 4] = wv;
        int g = R + r;
        float4 xv = make_float4(0.f, 0.f, 0.f, 0.f);
        if (g < NROWS) {
            int n = g >> 1, b = g & 1;
            xv = ((const float4*)(x + ((size_t)b * N_NODES + n) * NC))[c4];
        }
        *(float4*)&xs[r * 68 + c4 * 4] = xv;
    }
    __syncthreads();

    int tr = t >> 4, tc = t & 15;
    float acc[4][4];
#pragma unroll
    for (int i = 0; i < 4; i++)
#pragma unroll
        for (int j = 0; j < 4; j++) acc[i][j] = 0.f;

#pragma unroll 4
    for (int k4 = 0; k4 < 16; k4++) {
        float4 xv[4], wv[4];
#pragma unroll
        for (int i = 0; i < 4; i++)
            xv[i] = *(const float4*)&xs[(tr * 4 + i) * 68 + k4 * 4];
#pragma unroll
        for (int kk = 0; kk < 4; kk++)
            wv[kk] = *(const float4*)&Ws[(k4 * 4 + kk) * 68 + tc * 4];
#pragma unroll
        for (int i = 0; i < 4; i++) {
            acc[i][0] = fmaf(xv[i].x, wv[0].x, acc[i][0]);
            acc[i][1] = fmaf(xv[i].x, wv[0].y, acc[i][1]);
            acc[i][2] = fmaf(xv[i].x, wv[0].z, acc[i][2]);
            acc[i][3] = fmaf(xv[i].x, wv[0].w, acc[i][3]);
            acc[i][0] = fmaf(xv[i].y, wv[1].x, acc[i][0]);
            acc[i][1] = fmaf(xv[i].y, wv[1].y, acc[i][1]);
            acc[i][2] = fmaf(xv[i].y, wv[1].z, acc[i][2]);
            acc[i][3] = fmaf(xv[i].y, wv[1].w, acc[i][3]);
            acc[i][0] = fmaf(xv[i].z, wv[2].x, acc[i][0]);
            acc[i][1] = fmaf(xv[i].z, wv[2].y, acc[i][1]);
            acc[i][2] = fmaf(xv[i].z, wv[2].z, acc[i][2]);
            acc[i][3] = fmaf(xv[i].z, wv[2].w, acc[i][3]);
            acc[i][0] = fmaf(xv[i].w, wv[3].x, acc[i][0]);
            acc[i][1] = fmaf(xv[i].w, wv[3].y, acc[i][1]);
            acc[i][2] = fmaf(xv[i].w, wv[3].z, acc[i][2]);
            acc[i][3] = fmaf(xv[i].w, wv[3].w, acc[i][3]);
        }
    }

    float a1x = att[tc * 4], a1y = att[tc * 4 + 1], a1z = att[tc * 4 + 2], a1w = att[tc * 4 + 3];
    float a2x = att[64 + tc * 4], a2y = att[64 + tc * 4 + 1], a2z = att[64 + tc * 4 + 2], a2w = att[64 + tc * 4 + 3];
#pragma unroll
    for (int i = 0; i < 4; i++) {
        int g = R + tr * 4 + i;
        if (g < NROWS) {
            ushort4 bv;
            bv.x = f2bf(acc[i][0]); bv.y = f2bf(acc[i][1]);
            bv.z = f2bf(acc[i][2]); bv.w = f2bf(acc[i][3]);
            ((ushort4*)(xwb + (size_t)g * 64))[tc] = bv;
        }
        float v1 = acc[i][0] * a1x + acc[i][1] * a1y + acc[i][2] * a1z + acc[i][3] * a1w;
        float v2 = acc[i][0] * a2x + acc[i][1] * a2y + acc[i][2] * a2z + acc[i][3] * a2w;
#pragma unroll
        for (int off = 8; off >= 1; off >>= 1) {
            v1 += __shfl_xor(v1, off, 64);
            v2 += __shfl_xor(v2, off, 64);
        }
        if (tc == 0 && g < NROWS) { p1[g] = v1; p2[g] = v2; }
    }
}

// ---------------- count node degrees + hyperedge ranges (merged)
__global__ void count_kernel(const int* __restrict__ node_idx,
                             const int* __restrict__ hedge,
                             int* __restrict__ cnt, int* __restrict__ estart)
{
    int i = blockIdx.x * blockDim.x + threadIdx.x;
    if (i < N_EDGES) atomicAdd(&cnt[node_idx[i]], 1);
    if (i <= N_HEDGE) {
        int lo = 0, hi = N_EDGES;
        while (lo < hi) {
            int mid = (lo + hi) >> 1;
            if (hedge[mid] < i) lo = mid + 1; else hi = mid;
        }
        estart[i] = lo;
    }
}

// ---------------- hierarchical scan
__global__ __launch_bounds__(256) void scanA_kernel(const int* __restrict__ cnt,
                                                    int* __restrict__ nstart,
                                                    int* __restrict__ bsum)
{
    __shared__ int sm[256];
    int tid = threadIdx.x;
    int i = blockIdx.x * 256 + tid;
    int v = (i < N_NODES) ? cnt[i] : 0;
    sm[tid] = v;
    __syncthreads();
    for (int off = 1; off < 256; off <<= 1) {
        int t = (tid >= off) ? sm[tid - off] : 0;
        __syncthreads();
        sm[tid] += t;
        __syncthreads();
    }
    if (i < N_NODES) nstart[i] = sm[tid] - v;
    if (tid == 255) bsum[blockIdx.x] = sm[255];
}

__global__ __launch_bounds__(256) void scanB_kernel(int* __restrict__ bsum,
                                                    int* __restrict__ nstart, int nblocks)
{
    __shared__ int sm[256];
    int tid = threadIdx.x;
    int v = (tid < nblocks) ? bsum[tid] : 0;
    sm[tid] = v;
    __syncthreads();
    for (int off = 1; off < 256; off <<= 1) {
        int t = (tid >= off) ? sm[tid - off] : 0;
        __syncthreads();
        sm[tid] += t;
        __syncthreads();
    }
    if (tid < nblocks) bsum[tid] = sm[tid] - v;
    if (tid == 255) nstart[N_NODES] = sm[255];
}

__global__ void scanC_kernel(int* __restrict__ nstart, const int* __restrict__ bsum)
{
    int i = blockIdx.x * blockDim.x + threadIdx.x;
    if (i < N_NODES) nstart[i] += bsum[i >> 8];
}

// ---------------- scatter: CSR perm arrays (hperm + inverse entries)
__global__ void scatter_kernel(const int* __restrict__ node_idx,
                               const int* __restrict__ hedge_idx,
                               const int* __restrict__ nstart,
                               int* __restrict__ cursor,
                               int* __restrict__ hperm, int* __restrict__ entries)
{
    int e = blockIdx.x * blockDim.x + threadIdx.x;
    if (e >= N_EDGES) return;
    int n = node_idx[e];
    int p = nstart[n] + atomicAdd(&cursor[n], 1);
    hperm[p] = hedge_idx[e];
    entries[p] = e;
}

// ---------------- per-hyperedge: s2[h*2+b] = sum_{e in h} p2[node[e]*2+b]
__global__ __launch_bounds__(256) void hedge_kernel(const float* __restrict__ p2,
                                                    const int* __restrict__ node_idx,
                                                    const int* __restrict__ estart,
                                                    float* __restrict__ s2)
{
    int wv = blockIdx.x * 4 + (threadIdx.x >> 6);
    if (wv >= N_HEDGE) return;
    int lane = threadIdx.x & 63;
    int s = estart[wv], e1 = estart[wv + 1];
    float a0 = 0.f, a1 = 0.f;
    for (int e = s + lane; e < e1; e += 64) {
        int n = node_idx[e];
        float2 p = ((const float2*)p2)[n];
        a0 += p.x; a1 += p.y;
    }
#pragma unroll
    for (int off = 32; off >= 1; off >>= 1) {
        a0 += __shfl_xor(a0, off, 64);
        a1 += __shfl_xor(a1, off, 64);
    }
    if (lane == 0) {
        s2[wv * 2] = a0;
        s2[wv * 2 + 1] = a1;
    }
}

// ---------------- fused logits + leaky relu + softmax; emit CSR-order AND edge-order alpha
__global__ void softmax_kernel(const int* __restrict__ nstart,
                               const int* __restrict__ hperm,
                               const int* __restrict__ entries,
                               const float* __restrict__ p1,
                               const float* __restrict__ s2,
                               float* __restrict__ acsr,
                               float* __restrict__ aedge)
{
    int n = blockIdx.x * blockDim.x + threadIdx.x;
    if (n >= N_NODES) return;
    int s = nstart[n], e1 = nstart[n + 1];
    if (s == e1) return;
    float pn0 = p1[n * 2], pn1 = p1[n * 2 + 1];
    float2* a = (float2*)acsr;
    float2* ae = (float2*)aedge;
    const float2* s2v = (const float2*)s2;
    float mx0 = -INFINITY, mx1 = -INFINITY;
    for (int j = s; j < e1; j++) {
        int h = hperm[j];
        float2 sv = s2v[h];
        float r0 = pn0 + sv.x; r0 = (r0 >= 0.f) ? r0 : NEG * r0;
        float r1 = pn1 + sv.y; r1 = (r1 >= 0.f) ? r1 : NEG * r1;
        a[j] = make_float2(r0, r1);
        mx0 = fmaxf(mx0, r0); mx1 = fmaxf(mx1, r1);
    }
    float s0 = 0.f, s1 = 0.f;
    for (int j = s; j < e1; j++) {
        float2 v = a[j];
        s0 += expf(v.x - mx0); s1 += expf(v.y - mx1);
    }
    float i0 = 1.0f / s0, i1 = 1.0f / s1;
    for (int j = s; j < e1; j++) {
        float2 v = a[j];
        float2 o = make_float2(expf(v.x - mx0) * i0, expf(v.y - mx1) * i1);
        a[j] = o;
        ae[entries[j]] = o;      // edge-order copy for m_kernel (scattered write)
    }
}

// ---------------- pass 1: m[h][k] = (1/deg) * sum_{e in h} alpha[e,b(k)]*xw[node[e]][k]
// 256 thr = 4 waves split the edge list; lane l covers channels {2l,2l+1}; LDS combine.
__global__ __launch_bounds__(256) void m_kernel(const unsigned short* __restrict__ xwb,
                                                const int* __restrict__ node_idx,
                                                const int* __restrict__ estart,
                                                const float* __restrict__ aedge,
                                                float* __restrict__ m)
{
    __shared__ float red[3][128];
    int h = blockIdx.x;
    int t = threadIdx.x;
    int w = t >> 6, l = t & 63;
    int b = l >> 5;                       // channel 2l: b = (2l)>>6
    int s = estart[h], e1 = estart[h + 1];
    const float2* ae = (const float2*)aedge;
    float ax = 0.f, ay = 0.f;
    int e = s + w;
    for (; e + 12 < e1; e += 16) {
        int n0 = node_idx[e],     n1 = node_idx[e + 4];
        int n2 = node_idx[e + 8], n3 = node_idx[e + 12];
        float2 A0 = ae[e],     A1 = ae[e + 4];
        float2 A2 = ae[e + 8], A3 = ae[e + 12];
        float a0 = b ? A0.y : A0.x;
        float a1 = b ? A1.y : A1.x;
        float a2 = b ? A2.y : A2.x;
        float a3 = b ? A3.y : A3.x;
        unsigned int u0 = *(const unsigned int*)&xwb[(size_t)n0 * 128 + 2 * l];
        unsigned int u1 = *(const unsigned int*)&xwb[(size_t)n1 * 128 + 2 * l];
        unsigned int u2 = *(const unsigned int*)&xwb[(size_t)n2 * 128 + 2 * l];
        unsigned int u3 = *(const unsigned int*)&xwb[(size_t)n3 * 128 + 2 * l];
        ax = fmaf(a0, __uint_as_float(u0 << 16), ax);
        ay = fmaf(a0, __uint_as_float(u0 & 0xffff0000u), ay);
        ax = fmaf(a1, __uint_as_float(u1 << 16), ax);
        ay = fmaf(a1, __uint_as_float(u1 & 0xffff0000u), ay);
        ax = fmaf(a2, __uint_as_float(u2 << 16), ax);
        ay = fmaf(a2, __uint_as_float(u2 & 0xffff0000u), ay);
        ax = fmaf(a3, __uint_as_float(u3 << 16), ax);
        ay = fmaf(a3, __uint_as_float(u3 & 0xffff0000u), ay);
    }
    for (; e < e1; e += 4) {
        int n = node_idx[e];
        float2 A = ae[e];
        float a0 = b ? A.y : A.x;
        unsigned int u = *(const unsigned int*)&xwb[(size_t)n * 128 + 2 * l];
        ax = fmaf(a0, __uint_as_float(u << 16), ax);
        ay = fmaf(a0, __uint_as_float(u & 0xffff0000u), ay);
    }
    if (w) { red[w - 1][2 * l] = ax; red[w - 1][2 * l + 1] = ay; }
    __syncthreads();
    if (w == 0) {
        ax += red[0][2 * l] + red[1][2 * l] + red[2][2 * l];
        ay += red[0][2 * l + 1] + red[1][2 * l + 1] + red[2][2 * l + 1];
        int d = e1 - s;
        float binv = (d > 0) ? 1.0f / (float)d : 0.0f;
        ((float2*)(m + (size_t)h * 128))[l] = make_float2(binv * ax, binv * ay);
    }
}

// ---------------- pass 2: wave-per-node; out[b][n][c] = deg[n]*sum_j a[j,b]*m[hperm[j]][k]
__global__ __launch_bounds__(256) void out_kernel(const float* __restrict__ m,
                                                  const int* __restrict__ hperm,
                                                  const int* __restrict__ nstart,
                                                  const float* __restrict__ acsr,
                                                  float* __restrict__ out)
{
    int t = threadIdx.x;
    int w = t >> 6, l = t & 63;
    int n = blockIdx.x * 4 + w;
    if (n >= N_NODES) return;
    int b = l >> 5;
    int s = nstart[n], e1 = nstart[n + 1];
    const float2* av = (const float2*)acsr;
    float ax = 0.f, ay = 0.f;
    int j = s;
    for (; j + 3 < e1; j += 4) {
        int h0 = hperm[j],     h1 = hperm[j + 1];
        int h2 = hperm[j + 2], h3 = hperm[j + 3];
        float2 A0 = av[j],     A1 = av[j + 1];
        float2 A2 = av[j + 2], A3 = av[j + 3];
        float a0 = b ? A0.y : A0.x;
        float a1 = b ? A1.y : A1.x;
        float a2 = b ? A2.y : A2.x;
        float a3 = b ? A3.y : A3.x;
        float2 v0 = ((const float2*)(m + (size_t)h0 * 128))[l];
        float2 v1 = ((const float2*)(m + (size_t)h1 * 128))[l];
        float2 v2 = ((const float2*)(m + (size_t)h2 * 128))[l];
        float2 v3 = ((const float2*)(m + (size_t)h3 * 128))[l];
        ax = fmaf(a0, v0.x, ax); ay = fmaf(a0, v0.y, ay);
        ax = fmaf(a1, v1.x, ax); ay = fmaf(a1, v1.y, ay);
        ax = fmaf(a2, v2.x, ax); ay = fmaf(a2, v2.y, ay);
        ax = fmaf(a3, v3.x, ax); ay = fmaf(a3, v3.y, ay);
    }
    for (; j < e1; j++) {
        int h = hperm[j];
        float2 A = av[j];
        float a0 = b ? A.y : A.x;
        float2 v = ((const float2*)(m + (size_t)h * 128))[l];
        ax = fmaf(a0, v.x, ax); ay = fmaf(a0, v.y, ay);
    }
    float deg = (float)(e1 - s);
    int c = (2 * l) & 63;
    float* dst = out + (size_t)b * N_NODES * 64 + (size_t)n * 64 + c;
    __builtin_nontemporal_store(deg * ax, dst);
    __builtin_nontemporal_store(deg * ay, dst + 1);
}

extern "C" void kernel_launch(void* const* d_in, const int* in_sizes, int n_in,
                              void* d_out, int out_size, void* d_ws, size_t ws_size,
                              hipStream_t stream)
{
    const float* x      = (const float*)d_in[0];
    const float* W      = (const float*)d_in[1];
    const float* att    = (const float*)d_in[2];
    const int* node_idx = (const int*)d_in[3];
    const int* hedge_idx= (const int*)d_in[4];
    float* out = (float*)d_out;

    // workspace layout — ~26.4MB total
    unsigned short* xwb = (unsigned short*)d_ws;        // 6,400,000 ushort (12.8MB)
    float* p1     = (float*)(xwb + (size_t)NROWS * NC); // 100,000
    float* p2     = p1 + NROWS;                         // 100,000
    float* s2     = p2 + NROWS;                         // 10,000
    float* acsr   = s2 + 10000;                         // 800,000 (even offset -> 8B aligned)
    float* m      = acsr + 2 * N_EDGES;                 // 640,000
    float* aedge  = m + (size_t)N_HEDGE * NB * NC;      // 800,000 (even)
    int* estart  = (int*)(aedge + 2 * N_EDGES);         // 5,008 (padded)
    int* cnt     = estart + 5008;                       // 50,000
    int* cursor  = cnt + N_NODES;                       // 50,000 (contiguous with cnt)
    int* nstart  = cursor + N_NODES;                    // 50,008 (padded)
    int* bsum    = nstart + 50008;                      // 256
    int* hperm   = bsum + 256;                          // 400,000
    int* entries = hperm + N_EDGES;                     // 400,000

    const int SCAN_BLOCKS = (N_NODES + 255) / 256;      // 196

    hipMemsetAsync(cnt, 0, (size_t)2 * N_NODES * sizeof(int), stream);

    gemm_kernel<<<(NROWS + 63) / 64, 256, 0, stream>>>(x, W, att, xwb, p1, p2);
    count_kernel<<<(N_EDGES + 255) / 256, 256, 0, stream>>>(node_idx, hedge_idx, cnt, estart);
    scanA_kernel<<<SCAN_BLOCKS, 256, 0, stream>>>(cnt, nstart, bsum);
    scanB_kernel<<<1, 256, 0, stream>>>(bsum, nstart, SCAN_BLOCKS);
    scanC_kernel<<<SCAN_BLOCKS, 256, 0, stream>>>(nstart, bsum);
    scatter_kernel<<<(N_EDGES + 255) / 256, 256, 0, stream>>>(node_idx, hedge_idx, nstart,
                                                              cursor, hperm, entries);
    hedge_kernel<<<(N_HEDGE + 3) / 4, 256, 0, stream>>>(p2, node_idx, estart, s2);
    softmax_kernel<<<(N_NODES + 255) / 256, 256, 0, stream>>>(nstart, hperm, entries,
                                                              p1, s2, acsr, aedge);
    m_kernel<<<N_HEDGE, 256, 0, stream>>>(xwb, node_idx, estart, aedge, m);
    out_kernel<<<(N_NODES + 3) / 4, 256, 0, stream>>>(m, hperm, nstart, acsr, out);
}

// Round 12
// 225.987 us; speedup vs baseline: 1.0553x; 1.0553x over previous
//
#include <hip/hip_runtime.h>
#include <math.h>

#define N_NODES 50000
#define N_HEDGE 5000
#define N_EDGES 400000
#define NB 2
#define NC 64
#define NEG 0.2f
#define NROWS (N_NODES * NB)   // 100000

__device__ __forceinline__ unsigned short f2bf(float f) {
    unsigned int u = __float_as_uint(f);
    unsigned int r = (u + 0x7FFFu + ((u >> 16) & 1u)) >> 16;   // RNE
    return (unsigned short)r;
}

// ---------------- GEMM: xw[row][c] bf16, row = n*2+b; epilogue p1/p2
__global__ __launch_bounds__(256, 4) void gemm_kernel(const float* __restrict__ x,
                                                      const float* __restrict__ W,
                                                      const float* __restrict__ att,
                                                      unsigned short* __restrict__ xwb,
                                                      float* __restrict__ p1,
                                                      float* __restrict__ p2)
{
    __shared__ float xs[64 * 68];
    __shared__ float Ws[64 * 68];
    int t = threadIdx.x;
    int R = blockIdx.x * 64;

#pragma unroll
    for (int i = 0; i < 4; i++) {
        int lin = t + 256 * i;
        int r = lin >> 4, c4 = lin & 15;
        float4 wv = ((const float4*)W)[lin];
        *(float4*)&Ws[r * 68 + c4 * 4] = wv;
        int g = R + r;
        float4 xv = make_float4(0.f, 0.f, 0.f, 0.f);
        if (g < NROWS) {
            int n = g >> 1, b = g & 1;
            xv = ((const float4*)(x + ((size_t)b * N_NODES + n) * NC))[c4];
        }
        *(float4*)&xs[r * 68 + c4 * 4] = xv;
    }
    __syncthreads();

    int tr = t >> 4, tc = t & 15;
    float acc[4][4];
#pragma unroll
    for (int i = 0; i < 4; i++)
#pragma unroll
        for (int j = 0; j < 4; j++) acc[i][j] = 0.f;

#pragma unroll 4
    for (int k4 = 0; k4 < 16; k4++) {
        float4 xv[4], wv[4];
#pragma unroll
        for (int i = 0; i < 4; i++)
            xv[i] = *(const float4*)&xs[(tr * 4 + i) * 68 + k4 * 4];
#pragma unroll
        for (int kk = 0; kk < 4; kk++)
            wv[kk] = *(const float4*)&Ws[(k4 * 4 + kk) * 68 + tc * 4];
#pragma unroll
        for (int i = 0; i < 4; i++) {
            acc[i][0] = fmaf(xv[i].x, wv[0].x, acc[i][0]);
            acc[i][1] = fmaf(xv[i].x, wv[0].y, acc[i][1]);
            acc[i][2] = fmaf(xv[i].x, wv[0].z, acc[i][2]);
            acc[i][3] = fmaf(xv[i].x, wv[0].w, acc[i][3]);
            acc[i][0] = fmaf(xv[i].y, wv[1].x, acc[i][0]);
            acc[i][1] = fmaf(xv[i].y, wv[1].y, acc[i][1]);
            acc[i][2] = fmaf(xv[i].y, wv[1].z, acc[i][2]);
            acc[i][3] = fmaf(xv[i].y, wv[1].w, acc[i][3]);
            acc[i][0] = fmaf(xv[i].z, wv[2].x, acc[i][0]);
            acc[i][1] = fmaf(xv[i].z, wv[2].y, acc[i][1]);
            acc[i][2] = fmaf(xv[i].z, wv[2].z, acc[i][2]);
            acc[i][3] = fmaf(xv[i].z, wv[2].w, acc[i][3]);
            acc[i][0] = fmaf(xv[i].w, wv[3].x, acc[i][0]);
            acc[i][1] = fmaf(xv[i].w, wv[3].y, acc[i][1]);
            acc[i][2] = fmaf(xv[i].w, wv[3].z, acc[i][2]);
            acc[i][3] = fmaf(xv[i].w, wv[3].w, acc[i][3]);
        }
    }

    float a1x = att[tc * 4], a1y = att[tc * 4 + 1], a1z = att[tc * 4 + 2], a1w = att[tc * 4 + 3];
    float a2x = att[64 + tc * 4], a2y = att[64 + tc * 4 + 1], a2z = att[64 + tc * 4 + 2], a2w = att[64 + tc * 4 + 3];
#pragma unroll
    for (int i = 0; i < 4; i++) {
        int g = R + tr * 4 + i;
        if (g < NROWS) {
            ushort4 bv;
            bv.x = f2bf(acc[i][0]); bv.y = f2bf(acc[i][1]);
            bv.z = f2bf(acc[i][2]); bv.w = f2bf(acc[i][3]);
            ((ushort4*)(xwb + (size_t)g * 64))[tc] = bv;
        }
        float v1 = acc[i][0] * a1x + acc[i][1] * a1y + acc[i][2] * a1z + acc[i][3] * a1w;
        float v2 = acc[i][0] * a2x + acc[i][1] * a2y + acc[i][2] * a2z + acc[i][3] * a2w;
#pragma unroll
        for (int off = 8; off >= 1; off >>= 1) {
            v1 += __shfl_xor(v1, off, 64);
            v2 += __shfl_xor(v2, off, 64);
        }
        if (tc == 0 && g < NROWS) { p1[g] = v1; p2[g] = v2; }
    }
}

// ---------------- count node degrees + hyperedge ranges (merged)
__global__ void count_kernel(const int* __restrict__ node_idx,
                             const int* __restrict__ hedge,
                             int* __restrict__ cnt, int* __restrict__ estart)
{
    int i = blockIdx.x * blockDim.x + threadIdx.x;
    if (i < N_EDGES) atomicAdd(&cnt[node_idx[i]], 1);
    if (i <= N_HEDGE) {
        int lo = 0, hi = N_EDGES;
        while (lo < hi) {
            int mid = (lo + hi) >> 1;
            if (hedge[mid] < i) lo = mid + 1; else hi = mid;
        }
        estart[i] = lo;
    }
}

// ---------------- hierarchical scan
__global__ __launch_bounds__(256) void scanA_kernel(const int* __restrict__ cnt,
                                                    int* __restrict__ nstart,
                                                    int* __restrict__ bsum)
{
    __shared__ int sm[256];
    int tid = threadIdx.x;
    int i = blockIdx.x * 256 + tid;
    int v = (i < N_NODES) ? cnt[i] : 0;
    sm[tid] = v;
    __syncthreads();
    for (int off = 1; off < 256; off <<= 1) {
        int t = (tid >= off) ? sm[tid - off] : 0;
        __syncthreads();
        sm[tid] += t;
        __syncthreads();
    }
    if (i < N_NODES) nstart[i] = sm[tid] - v;
    if (tid == 255) bsum[blockIdx.x] = sm[255];
}

__global__ __launch_bounds__(256) void scanB_kernel(int* __restrict__ bsum,
                                                    int* __restrict__ nstart, int nblocks)
{
    __shared__ int sm[256];
    int tid = threadIdx.x;
    int v = (tid < nblocks) ? bsum[tid] : 0;
    sm[tid] = v;
    __syncthreads();
    for (int off = 1; off < 256; off <<= 1) {
        int t = (tid >= off) ? sm[tid - off] : 0;
        __syncthreads();
        sm[tid] += t;
        __syncthreads();
    }
    if (tid < nblocks) bsum[tid] = sm[tid] - v;
    if (tid == 255) nstart[N_NODES] = sm[255];
}

__global__ void scanC_kernel(int* __restrict__ nstart, const int* __restrict__ bsum)
{
    int i = blockIdx.x * blockDim.x + threadIdx.x;
    if (i < N_NODES) nstart[i] += bsum[i >> 8];
}

// ---------------- scatter: CSR perm arrays
__global__ void scatter_kernel(const int* __restrict__ node_idx,
                               const int* __restrict__ hedge_idx,
                               const int* __restrict__ nstart,
                               int* __restrict__ cursor,
                               int* __restrict__ hperm, int* __restrict__ pos)
{
    int e = blockIdx.x * blockDim.x + threadIdx.x;
    if (e >= N_EDGES) return;
    int n = node_idx[e];
    int p = nstart[n] + atomicAdd(&cursor[n], 1);
    hperm[p] = hedge_idx[e];
    pos[e] = p;
}

// ---------------- per-hyperedge: s2[h*2+b] = sum_{e in h} p2[node[e]*2+b]
__global__ __launch_bounds__(256) void hedge_kernel(const float* __restrict__ p2,
                                                    const int* __restrict__ node_idx,
                                                    const int* __restrict__ estart,
                                                    float* __restrict__ s2)
{
    int wv = blockIdx.x * 4 + (threadIdx.x >> 6);
    if (wv >= N_HEDGE) return;
    int lane = threadIdx.x & 63;
    int s = estart[wv], e1 = estart[wv + 1];
    float a0 = 0.f, a1 = 0.f;
    for (int e = s + lane; e < e1; e += 64) {
        int n = node_idx[e];
        float2 p = ((const float2*)p2)[n];
        a0 += p.x; a1 += p.y;
    }
#pragma unroll
    for (int off = 32; off >= 1; off >>= 1) {
        a0 += __shfl_xor(a0, off, 64);
        a1 += __shfl_xor(a1, off, 64);
    }
    if (lane == 0) {
        s2[wv * 2] = a0;
        s2[wv * 2 + 1] = a1;
    }
}

// ---------------- fused logits + leaky relu + per-node softmax (CSR order, in place)
// pass 2 stores exp values (no recompute in pass 3)
__global__ void softmax_kernel(const int* __restrict__ nstart,
                               const int* __restrict__ hperm,
                               const float* __restrict__ p1,
                               const float* __restrict__ s2,
                               float* __restrict__ acsr)
{
    int n = blockIdx.x * blockDim.x + threadIdx.x;
    if (n >= N_NODES) return;
    int s = nstart[n], e1 = nstart[n + 1];
    if (s == e1) return;
    float pn0 = p1[n * 2], pn1 = p1[n * 2 + 1];
    float2* a = (float2*)acsr;
    const float2* s2v = (const float2*)s2;
    float mx0 = -INFINITY, mx1 = -INFINITY;
    for (int j = s; j < e1; j++) {
        int h = hperm[j];
        float2 sv = s2v[h];
        float r0 = pn0 + sv.x; r0 = (r0 >= 0.f) ? r0 : NEG * r0;
        float r1 = pn1 + sv.y; r1 = (r1 >= 0.f) ? r1 : NEG * r1;
        a[j] = make_float2(r0, r1);
        mx0 = fmaxf(mx0, r0); mx1 = fmaxf(mx1, r1);
    }
    float s0 = 0.f, s1 = 0.f;
    for (int j = s; j < e1; j++) {
        float2 v = a[j];
        float e0 = expf(v.x - mx0), e1f = expf(v.y - mx1);
        a[j] = make_float2(e0, e1f);
        s0 += e0; s1 += e1f;
    }
    float i0 = 1.0f / s0, i1 = 1.0f / s1;
    for (int j = s; j < e1; j++) {
        float2 v = a[j];
        a[j] = make_float2(v.x * i0, v.y * i1);
    }
}

// ---------------- pass 1: m[h][k] = (1/deg) * sum_{e in h} alpha[e,b(k)]*xw[node[e]][k]
// lane l covers channels {2l, 2l+1}; wave w handles edges s+w, s+w+2, ...; LDS combine.
__global__ __launch_bounds__(128) void m_kernel(const unsigned short* __restrict__ xwb,
                                                const int* __restrict__ node_idx,
                                                const int* __restrict__ estart,
                                                const int* __restrict__ pos,
                                                const float* __restrict__ acsr,
                                                float* __restrict__ m)
{
    __shared__ float red[128];
    int h = blockIdx.x;
    int t = threadIdx.x;
    int w = t >> 6, l = t & 63;
    int b = l >> 5;                       // channel 2l: b = (2l)>>6
    int s = estart[h], e1 = estart[h + 1];
    float ax = 0.f, ay = 0.f;
    int e = s + w;
    for (; e + 6 < e1; e += 8) {
        int n0 = node_idx[e],     n1 = node_idx[e + 2];
        int n2 = node_idx[e + 4], n3 = node_idx[e + 6];
        int q0 = pos[e],     q1 = pos[e + 2];
        int q2 = pos[e + 4], q3 = pos[e + 6];
        float a0 = acsr[q0 * 2 + b], a1 = acsr[q1 * 2 + b];
        float a2 = acsr[q2 * 2 + b], a3 = acsr[q3 * 2 + b];
        unsigned int u0 = *(const unsigned int*)&xwb[(size_t)n0 * 128 + 2 * l];
        unsigned int u1 = *(const unsigned int*)&xwb[(size_t)n1 * 128 + 2 * l];
        unsigned int u2 = *(const unsigned int*)&xwb[(size_t)n2 * 128 + 2 * l];
        unsigned int u3 = *(const unsigned int*)&xwb[(size_t)n3 * 128 + 2 * l];
        ax = fmaf(a0, __uint_as_float(u0 << 16), ax);
        ay = fmaf(a0, __uint_as_float(u0 & 0xffff0000u), ay);
        ax = fmaf(a1, __uint_as_float(u1 << 16), ax);
        ay = fmaf(a1, __uint_as_float(u1 & 0xffff0000u), ay);
        ax = fmaf(a2, __uint_as_float(u2 << 16), ax);
        ay = fmaf(a2, __uint_as_float(u2 & 0xffff0000u), ay);
        ax = fmaf(a3, __uint_as_float(u3 << 16), ax);
        ay = fmaf(a3, __uint_as_float(u3 & 0xffff0000u), ay);
    }
    for (; e < e1; e += 2) {
        int n = node_idx[e];
        float a0 = acsr[pos[e] * 2 + b];
        unsigned int u = *(const unsigned int*)&xwb[(size_t)n * 128 + 2 * l];
        ax = fmaf(a0, __uint_as_float(u << 16), ax);
        ay = fmaf(a0, __uint_as_float(u & 0xffff0000u), ay);
    }
    if (w == 1) { red[2 * l] = ax; red[2 * l + 1] = ay; }
    __syncthreads();
    if (w == 0) {
        ax += red[2 * l]; ay += red[2 * l + 1];
        int d = e1 - s;
        float binv = (d > 0) ? 1.0f / (float)d : 0.0f;
        ((float2*)(m + (size_t)h * 128))[l] = make_float2(binv * ax, binv * ay);
    }
}

// ---------------- pass 2: out[b][n][c] = deg[n] * sum_j alpha_csr[j,b]*m[hperm[j]][k]
__global__ __launch_bounds__(128) void out_kernel(const float* __restrict__ m,
                                                  const int* __restrict__ hperm,
                                                  const int* __restrict__ nstart,
                                                  const float* __restrict__ acsr,
                                                  float* __restrict__ out)
{
    __shared__ float red[128];
    int n = blockIdx.x;
    int t = threadIdx.x;
    int w = t >> 6, l = t & 63;
    int b = l >> 5;
    int s = nstart[n], e1 = nstart[n + 1];
    float ax = 0.f, ay = 0.f;
    int j = s + w;
    for (; j + 6 < e1; j += 8) {
        int h0 = hperm[j],     h1 = hperm[j + 2];
        int h2 = hperm[j + 4], h3 = hperm[j + 6];
        float a0 = acsr[j * 2 + b],       a1 = acsr[(j + 2) * 2 + b];
        float a2 = acsr[(j + 4) * 2 + b], a3 = acsr[(j + 6) * 2 + b];
        float2 v0 = ((const float2*)(m + (size_t)h0 * 128))[l];
        float2 v1 = ((const float2*)(m + (size_t)h1 * 128))[l];
        float2 v2 = ((const float2*)(m + (size_t)h2 * 128))[l];
        float2 v3 = ((const float2*)(m + (size_t)h3 * 128))[l];
        ax = fmaf(a0, v0.x, ax); ay = fmaf(a0, v0.y, ay);
        ax = fmaf(a1, v1.x, ax); ay = fmaf(a1, v1.y, ay);
        ax = fmaf(a2, v2.x, ax); ay = fmaf(a2, v2.y, ay);
        ax = fmaf(a3, v3.x, ax); ay = fmaf(a3, v3.y, ay);
    }
    for (; j < e1; j += 2) {
        int h = hperm[j];
        float a0 = acsr[j * 2 + b];
        float2 v = ((const float2*)(m + (size_t)h * 128))[l];
        ax = fmaf(a0, v.x, ax); ay = fmaf(a0, v.y, ay);
    }
    if (w == 1) { red[2 * l] = ax; red[2 * l + 1] = ay; }
    __syncthreads();
    if (w == 0) {
        ax += red[2 * l]; ay += red[2 * l + 1];
        float deg = (float)(e1 - s);
        int c = (2 * l) & 63;
        float2 val = make_float2(deg * ax, deg * ay);
        float2* dst = (float2*)(out + (size_t)b * N_NODES * 64 + (size_t)n * 64 + c);
        __builtin_nontemporal_store(val.x, &((float*)dst)[0]);
        __builtin_nontemporal_store(val.y, &((float*)dst)[1]);
    }
}

extern "C" void kernel_launch(void* const* d_in, const int* in_sizes, int n_in,
                              void* d_out, int out_size, void* d_ws, size_t ws_size,
                              hipStream_t stream)
{
    const float* x      = (const float*)d_in[0];
    const float* W      = (const float*)d_in[1];
    const float* att    = (const float*)d_in[2];
    const int* node_idx = (const int*)d_in[3];
    const int* hedge_idx= (const int*)d_in[4];
    float* out = (float*)d_out;

    // workspace layout — ~23.2MB total
    unsigned short* xwb = (unsigned short*)d_ws;      // 6,400,000 ushort (12.8MB)
    float* p1     = (float*)(xwb + (size_t)NROWS * NC); // 100,000
    float* p2     = p1 + NROWS;                       // 100,000
    float* s2     = p2 + NROWS;                       // 10,000
    float* acsr   = s2 + 10000;                       // 800,000
    float* m      = acsr + 2 * N_EDGES;               // 640,000
    int* estart  = (int*)(m + (size_t)N_HEDGE * NB * NC); // 5,008 (padded)
    int* cnt     = estart + 5008;                     // 50,000
    int* cursor  = cnt + N_NODES;                     // 50,000 (contiguous with cnt)
    int* nstart  = cursor + N_NODES;                  // 50,008 (padded)
    int* bsum    = nstart + 50008;                    // 256
    int* hperm   = bsum + 256;                        // 400,000
    int* pos     = hperm + N_EDGES;                   // 400,000

    const int SCAN_BLOCKS = (N_NODES + 255) / 256;    // 196

    hipMemsetAsync(cnt, 0, (size_t)2 * N_NODES * sizeof(int), stream);

    gemm_kernel<<<(NROWS + 63) / 64, 256, 0, stream>>>(x, W, att, xwb, p1, p2);
    count_kernel<<<(N_EDGES + 255) / 256, 256, 0, stream>>>(node_idx, hedge_idx, cnt, estart);
    scanA_kernel<<<SCAN_BLOCKS, 256, 0, stream>>>(cnt, nstart, bsum);
    scanB_kernel<<<1, 256, 0, stream>>>(bsum, nstart, SCAN_BLOCKS);
    scanC_kernel<<<SCAN_BLOCKS, 256, 0, stream>>>(nstart, bsum);
    scatter_kernel<<<(N_EDGES + 255) / 256, 256, 0, stream>>>(node_idx, hedge_idx, nstart,
                                                              cursor, hperm, pos);
    hedge_kernel<<<(N_HEDGE + 3) / 4, 256, 0, stream>>>(p2, node_idx, estart, s2);
    softmax_kernel<<<(N_NODES + 255) / 256, 256, 0, stream>>>(nstart, hperm, p1, s2, acsr);
    m_kernel<<<N_HEDGE, 128, 0, stream>>>(xwb, node_idx, estart, pos, acsr, m);
    out_kernel<<<N_NODES, 128, 0, stream>>>(m, hperm, nstart, acsr, out);
}